// Round 4
// baseline (547.727 us; speedup 1.0000x reference)
//
#include <hip/hip_runtime.h>
#include <hip/hip_bf16.h>

#define KD   544      // 512 state + x0,x1,1 + pad to 17*32
#define ASTR 552      // LDS row stride (bf16)
#define RPB  32       // rows per block (2 blocks/CU)
#define MT   2        // row m-tiles (RPB/16)
#define THR  512      // 8 waves
#define T1   3        // pass-1 step count
#define NROW 32768

typedef __bf16 bf8 __attribute__((ext_vector_type(8)));
typedef float f32x4 __attribute__((ext_vector_type(4)));

__device__ __forceinline__ float sigm(float x)  { return 1.0f / (1.0f + __expf(-x)); }
__device__ __forceinline__ float tanh_(float x) { return 2.0f / (1.0f + __expf(-2.0f * x)) - 1.0f; }

// Coalesced pack via LDS tile transpose (unchanged from R3).
__global__ void pack_all(const float* __restrict__ Wi_h, const float* __restrict__ Wf_h,
                         const float* __restrict__ Wc_h, const float* __restrict__ Wo_h,
                         const float* __restrict__ Wi_x, const float* __restrict__ Wf_x,
                         const float* __restrict__ Wc_x, const float* __restrict__ Wo_x,
                         const float* __restrict__ bi_x, const float* __restrict__ bf_x,
                         const float* __restrict__ bc_x, const float* __restrict__ bo_x,
                         const float* __restrict__ bi_h, const float* __restrict__ bf_h,
                         const float* __restrict__ bc_h, const float* __restrict__ bo_h,
                         const float* __restrict__ outW1, const float* __restrict__ outb1,
                         const float* __restrict__ haltW1, const float* __restrict__ haltb1,
                         const float* __restrict__ outW2, const float* __restrict__ outb2,
                         const float* __restrict__ outW3, const float* __restrict__ outb3,
                         __bf16* __restrict__ whT, __bf16* __restrict__ w1cat,
                         float* __restrict__ w23, float* __restrict__ b23,
                         int* __restrict__ cntp)
{
  __shared__ float tile[64][65];
  const int b = blockIdx.x;
  const int tid = threadIdx.x;

  if (b < 256) {
    const int g = b >> 6, ct = (b >> 3) & 7, kt = b & 7;
    const int c0 = ct * 64, k0 = kt * 64;
    const float* Wh = (g == 0) ? Wi_h : (g == 1) ? Wf_h : (g == 2) ? Wc_h : Wo_h;
    const int ty = tid >> 6, tx = tid & 63;
#pragma unroll
    for (int r = 0; r < 16; ++r) {
      int kl = r * 4 + ty;
      tile[kl][tx] = Wh[(size_t)(k0 + kl) * 512 + c0 + tx];
    }
    __syncthreads();
    const int jj = tid >> 2, kq = tid & 3;
    bf8 lo, hi;
#pragma unroll
    for (int i = 0; i < 8; ++i) lo[i] = (__bf16)tile[kq * 16 + i][jj];
#pragma unroll
    for (int i = 0; i < 8; ++i) hi[i] = (__bf16)tile[kq * 16 + 8 + i][jj];
    __bf16* dst = whT + (size_t)(g * 512 + c0 + jj) * KD + k0 + kq * 16;
    *(bf8*)dst = lo;
    *(bf8*)(dst + 8) = hi;
  } else if (b < 288) {
    const int b2 = b - 256;
    const int g = b2 >> 3, ct = b2 & 7;
    const float* Wx = (g == 0) ? Wi_x : (g == 1) ? Wf_x : (g == 2) ? Wc_x : Wo_x;
    const float* bx = (g == 0) ? bi_x : (g == 1) ? bf_x : (g == 2) ? bc_x : bo_x;
    const float* bh = (g == 0) ? bi_h : (g == 1) ? bf_h : (g == 2) ? bc_h : bo_h;
    const int jj = tid >> 2, kq = tid & 3;
    const int c = ct * 64 + jj;
    bf8 v;
#pragma unroll
    for (int i = 0; i < 8; ++i) {
      int k = 512 + kq * 8 + i;
      float f = 0.0f;
      if (k == 512)      f = Wx[c];
      else if (k == 513) f = Wx[512 + c];
      else if (k == 514) f = bx[c] + bh[c];
      v[i] = (__bf16)f;
    }
    *(bf8*)(whT + (size_t)(g * 512 + c) * KD + 512 + kq * 8) = v;
  } else if (b < 320) {
    const int b2 = b - 288;
    const int src = b2 >> 4, jt = (b2 >> 3) & 1, kt = b2 & 7;
    const float* W = src ? haltW1 : outW1;
    const int c0 = jt * 64, k0 = kt * 64;
    const int ty = tid >> 6, tx = tid & 63;
#pragma unroll
    for (int r = 0; r < 16; ++r) {
      int kl = r * 4 + ty;
      tile[kl][tx] = W[(size_t)(k0 + kl) * 128 + c0 + tx];
    }
    __syncthreads();
    const int jj = tid >> 2, kq = tid & 3;
    bf8 lo, hi;
#pragma unroll
    for (int i = 0; i < 8; ++i) lo[i] = (__bf16)tile[kq * 16 + i][jj];
#pragma unroll
    for (int i = 0; i < 8; ++i) hi[i] = (__bf16)tile[kq * 16 + 8 + i][jj];
    __bf16* dst = w1cat + (size_t)(src * 128 + c0 + jj) * KD + k0 + kq * 16;
    *(bf8*)dst = lo;
    *(bf8*)(dst + 8) = hi;
  } else if (b < 324) {
    const int b2 = b - 320;
    const int jj = tid >> 2, kq = tid & 3;
    const int j = b2 * 64 + jj;
    const float bias = (j < 128) ? outb1[j] : haltb1[j - 128];
    bf8 v;
#pragma unroll
    for (int i = 0; i < 8; ++i) {
      int k = 512 + kq * 8 + i;
      v[i] = (__bf16)((k == 514) ? bias : 0.0f);
    }
    *(bf8*)(w1cat + (size_t)j * KD + 512 + kq * 8) = v;
  } else {
    const int c1 = tid;
    if (c1 < 128) {
      float s = 0.0f;
      for (int c2 = 0; c2 < 128; ++c2) s += outW2[c1 * 128 + c2] * outW3[c2];
      w23[c1] = s;
    }
    if (c1 == 0) {
      float bb = 0.0f;
      for (int c2 = 0; c2 < 128; ++c2) bb += outb2[c2] * outW3[c2];
      b23[0] = bb + outb3[0];
      cntp[0] = 0;
    }
  }
}

template<bool P1>
__global__ __launch_bounds__(THR, 4) void act_pass(
    const float* __restrict__ x,
    const __bf16* __restrict__ whT,
    const __bf16* __restrict__ w1cat,
    const float* __restrict__ w23,
    const float* __restrict__ b23p,
    const float* __restrict__ haltW2,
    const float* __restrict__ haltb2,
    __bf16* __restrict__ sstate,
    __bf16* __restrict__ scell,
    float* __restrict__ spsum,
    float* __restrict__ saccum,
    int* __restrict__ sidx,
    int* __restrict__ cntp,
    float* __restrict__ out)
{
  int cnt_v = 0, sbase = 0;
  if constexpr (!P1) {
    cnt_v = cntp[0];
    sbase = blockIdx.x * RPB;
    if (sbase >= cnt_v) return;
  }

  __shared__ __align__(16) __bf16 Abuf[2][RPB][ASTR];
  __shared__ float wv[256];
  __shared__ float partials[8][RPB];
  __shared__ int anyact_s;
  __shared__ int rowslot[RPB];

  const int tid  = threadIdx.x;
  const int wave = tid >> 6;
  const int lane = tid & 63;
  const int lg   = lane >> 4;
  const int lc   = lane & 15;
  const int row0 = blockIdx.x * RPB;

  if (tid < 256) wv[tid] = (tid < 128) ? w23[tid] : haltW2[tid - 128];

  if constexpr (P1) {
    for (int w = tid; w < 2 * RPB * 69; w += THR) {
      int bb  = w / (RPB * 69);
      int rem = w - bb * (RPB * 69);
      int r   = rem / 69;
      int j   = rem - r * 69;
      bf8 v;
#pragma unroll
      for (int e = 0; e < 8; ++e) v[e] = (__bf16)0.0f;
      if (j == 64) {
        v[0] = (__bf16)x[(row0 + r) * 2 + 0];
        v[1] = (__bf16)x[(row0 + r) * 2 + 1];
        v[2] = (__bf16)1.0f;
      }
      *(bf8*)&Abuf[bb][r][j * 8] = v;
    }
  } else {
    for (int w = tid; w < RPB * 68; w += THR) {
      int r = w / 68, j = w - r * 68;
      int slot = sbase + r;
      bf8 v;
#pragma unroll
      for (int e = 0; e < 8; ++e) v[e] = (__bf16)0.0f;
      if (slot < cnt_v) v = *(const bf8*)(sstate + (size_t)slot * KD + j * 8);
      *(bf8*)&Abuf[0][r][j * 8] = v;
      if (j >= 64) *(bf8*)&Abuf[1][r][j * 8] = v;
    }
    for (int w = tid; w < RPB * 64; w += THR) {
      int r = w / 64, j = w - r * 64;
      int slot = sbase + r;
      bf8 v;
#pragma unroll
      for (int e = 0; e < 8; ++e) v[e] = (__bf16)0.0f;
      if (slot < cnt_v) v = *(const bf8*)(scell + (size_t)slot * 512 + j * 8);
      *(bf8*)&Abuf[1][r][j * 8] = v;
    }
  }
  if (tid == 0) anyact_s = 1;
  __syncthreads();

  float cell[4][MT][4];
  if constexpr (P1) {
#pragma unroll
    for (int n = 0; n < 4; ++n)
#pragma unroll
      for (int m = 0; m < MT; ++m)
#pragma unroll
        for (int q = 0; q < 4; ++q) cell[n][m][q] = 0.0f;
  } else {
#pragma unroll
    for (int n = 0; n < 4; ++n)
#pragma unroll
      for (int m = 0; m < MT; ++m)
#pragma unroll
        for (int q = 0; q < 4; ++q)
          cell[n][m][q] = (float)Abuf[1][m * 16 + lg * 4 + q][wave * 64 + n * 16 + lc];
  }

  bool  valid, active;
  float p_sum, accum;
  int   oidx;
  if constexpr (P1) {
    valid = (tid < RPB); active = valid;
    p_sum = 0.0f; accum = 0.0f; oidx = row0 + tid;
  } else {
    int slot = sbase + tid;
    valid = (tid < RPB) && (slot < cnt_v);
    active = valid;
    p_sum = valid ? spsum[slot]  : 1.0f;
    accum = valid ? saccum[slot] : 0.0f;
    oidx  = valid ? sidx[slot]   : 0;
    __syncthreads();
  }

  const float b23 = b23p[0];
  const float bh2 = haltb2[0];
  const f32x4 zero4 = {0.0f, 0.0f, 0.0f, 0.0f};

  int cur = 0;
  const int T0 = P1 ? 0 : T1;
  const int TE = P1 ? T1 : 32;
  for (int t = T0; t < TE; ++t) {
    const int kstart = (P1 && t == 0) ? 16 : 0;
    // ---------------- gate GEMM (RPB x 2048) + LSTM update ----------------
#pragma unroll
    for (int n = 0; n < 4; ++n) {
      const int colb = wave * 64 + n * 16 + lc;
      const __bf16* bp0 = whT + (size_t)(colb)        * KD + lg * 8;
      const __bf16* bp1 = whT + (size_t)(512  + colb) * KD + lg * 8;
      const __bf16* bp2 = whT + (size_t)(1024 + colb) * KD + lg * 8;
      const __bf16* bp3 = whT + (size_t)(1536 + colb) * KD + lg * 8;
      f32x4 acc[4][MT];
#pragma unroll
      for (int g = 0; g < 4; ++g)
#pragma unroll
        for (int m = 0; m < MT; ++m) acc[g][m] = zero4;

      bf8 b0 = *(const bf8*)(bp0 + kstart * 32);
      bf8 b1 = *(const bf8*)(bp1 + kstart * 32);
      bf8 b2 = *(const bf8*)(bp2 + kstart * 32);
      bf8 b3 = *(const bf8*)(bp3 + kstart * 32);
#pragma unroll 1
      for (int kk = kstart; kk < 16; ++kk) {
        bf8 av[MT];
#pragma unroll
        for (int m = 0; m < MT; ++m)
          av[m] = *(const bf8*)&Abuf[cur][m * 16 + lc][kk * 32 + lg * 8];
        bf8 nb0 = *(const bf8*)(bp0 + (kk + 1) * 32);
        bf8 nb1 = *(const bf8*)(bp1 + (kk + 1) * 32);
        bf8 nb2 = *(const bf8*)(bp2 + (kk + 1) * 32);
        bf8 nb3 = *(const bf8*)(bp3 + (kk + 1) * 32);
#pragma unroll
        for (int m = 0; m < MT; ++m) {
          acc[0][m] = __builtin_amdgcn_mfma_f32_16x16x32_bf16(av[m], b0, acc[0][m], 0, 0, 0);
          acc[1][m] = __builtin_amdgcn_mfma_f32_16x16x32_bf16(av[m], b1, acc[1][m], 0, 0, 0);
          acc[2][m] = __builtin_amdgcn_mfma_f32_16x16x32_bf16(av[m], b2, acc[2][m], 0, 0, 0);
          acc[3][m] = __builtin_amdgcn_mfma_f32_16x16x32_bf16(av[m], b3, acc[3][m], 0, 0, 0);
        }
        b0 = nb0; b1 = nb1; b2 = nb2; b3 = nb3;
      }
      { // tail k-step (x0,x1,bias rows)
        bf8 av[MT];
#pragma unroll
        for (int m = 0; m < MT; ++m)
          av[m] = *(const bf8*)&Abuf[cur][m * 16 + lc][16 * 32 + lg * 8];
#pragma unroll
        for (int m = 0; m < MT; ++m) {
          acc[0][m] = __builtin_amdgcn_mfma_f32_16x16x32_bf16(av[m], b0, acc[0][m], 0, 0, 0);
          acc[1][m] = __builtin_amdgcn_mfma_f32_16x16x32_bf16(av[m], b1, acc[1][m], 0, 0, 0);
          acc[2][m] = __builtin_amdgcn_mfma_f32_16x16x32_bf16(av[m], b2, acc[2][m], 0, 0, 0);
          acc[3][m] = __builtin_amdgcn_mfma_f32_16x16x32_bf16(av[m], b3, acc[3][m], 0, 0, 0);
        }
      }
#pragma unroll
      for (int m = 0; m < MT; ++m) {
#pragma unroll
        for (int q = 0; q < 4; ++q) {
          float iv = sigm(acc[0][m][q]);
          float fv = sigm(acc[1][m][q]);
          float cv = tanh_(acc[2][m][q]);
          float ov = sigm(acc[3][m][q]);
          float cn = fv * cell[n][m][q] + iv * cv;
          cell[n][m][q] = cn;
          float h = ov * tanh_(cn);
          Abuf[cur ^ 1][m * 16 + lg * 4 + q][colb] = (__bf16)h;
        }
      }
    }
    __syncthreads();
    // ---------------- head GEMM (RPB x 256 = out|halt) + folded dots ----------------
    {
      const int jb0 = wave * 32 + lc;
      const __bf16* hp0 = w1cat + (size_t)jb0        * KD + lg * 8;
      const __bf16* hp1 = w1cat + (size_t)(jb0 + 16) * KD + lg * 8;
      f32x4 hacc[2][MT];
#pragma unroll
      for (int n2 = 0; n2 < 2; ++n2)
#pragma unroll
        for (int m = 0; m < MT; ++m) hacc[n2][m] = zero4;
      bf8 hb0 = *(const bf8*)(hp0);
      bf8 hb1 = *(const bf8*)(hp1);
#pragma unroll 1
      for (int kk = 0; kk < 16; ++kk) {
        bf8 av[MT];
#pragma unroll
        for (int m = 0; m < MT; ++m)
          av[m] = *(const bf8*)&Abuf[cur ^ 1][m * 16 + lc][kk * 32 + lg * 8];
        bf8 nb0 = *(const bf8*)(hp0 + (kk + 1) * 32);
        bf8 nb1 = *(const bf8*)(hp1 + (kk + 1) * 32);
#pragma unroll
        for (int m = 0; m < MT; ++m) {
          hacc[0][m] = __builtin_amdgcn_mfma_f32_16x16x32_bf16(av[m], hb0, hacc[0][m], 0, 0, 0);
          hacc[1][m] = __builtin_amdgcn_mfma_f32_16x16x32_bf16(av[m], hb1, hacc[1][m], 0, 0, 0);
        }
        hb0 = nb0; hb1 = nb1;
      }
      {
        bf8 av[MT];
#pragma unroll
        for (int m = 0; m < MT; ++m)
          av[m] = *(const bf8*)&Abuf[cur ^ 1][m * 16 + lc][16 * 32 + lg * 8];
#pragma unroll
        for (int m = 0; m < MT; ++m) {
          hacc[0][m] = __builtin_amdgcn_mfma_f32_16x16x32_bf16(av[m], hb0, hacc[0][m], 0, 0, 0);
          hacc[1][m] = __builtin_amdgcn_mfma_f32_16x16x32_bf16(av[m], hb1, hacc[1][m], 0, 0, 0);
        }
      }
      const float wv0 = wv[wave * 32 + lc];
      const float wv1 = wv[wave * 32 + 16 + lc];
#pragma unroll
      for (int m = 0; m < MT; ++m) {
#pragma unroll
        for (int q = 0; q < 4; ++q) {
          float s = fmaxf(hacc[0][m][q], 0.0f) * wv0 + fmaxf(hacc[1][m][q], 0.0f) * wv1;
          s += __shfl_xor(s, 1, 64);
          s += __shfl_xor(s, 2, 64);
          s += __shfl_xor(s, 4, 64);
          s += __shfl_xor(s, 8, 64);
          if (lc == 0) partials[wave][m * 16 + lg * 4 + q] = s;
        }
      }
    }
    __syncthreads();
    // ---------------- ACT bookkeeping ----------------
    if (tid < RPB) {
      float od = partials[0][tid] + partials[1][tid] + partials[2][tid] + partials[3][tid] + b23;
      float hd = partials[4][tid] + partials[5][tid] + partials[6][tid] + partials[7][tid] + bh2;
      float outv  = sigm(od);
      float haltv = sigm(hd);
      if (active) {
        float pn  = p_sum + haltv;
        bool  fin = (pn >= 0.999f) || (t == 31);
        accum += outv * (fin ? (haltv + (1.0f - pn)) : haltv);
        p_sum  = fin ? 1.0f : pn;
        active = !fin;
      }
      unsigned long long mk = __ballot(active);
      if (tid == 0) anyact_s = (mk != 0ull) ? 1 : 0;
    }
    __syncthreads();
    if (!anyact_s) break;
    cur ^= 1;
  }

  if constexpr (P1) {
    if (tid < RPB) {
      unsigned long long mk = __ballot(active);
      int base = 0;
      if (lane == 0 && mk) base = atomicAdd(cntp, __popcll(mk));
      base = __shfl(base, 0, 64);
      int rank = __popcll(mk & ((1ull << lane) - 1ull));
      int slot = active ? (base + rank) : -1;
      rowslot[tid] = slot;
      if (active) {
        spsum[slot]  = p_sum;
        saccum[slot] = accum;
        sidx[slot]   = oidx;
      } else {
        out[oidx] = accum;
      }
      if (tid == 0) anyact_s = (mk != 0ull) ? 1 : 0;
    }
    __syncthreads();
    if (anyact_s) {
#pragma unroll
      for (int n = 0; n < 4; ++n)
#pragma unroll
        for (int m = 0; m < MT; ++m)
#pragma unroll
          for (int q = 0; q < 4; ++q)
            Abuf[cur ^ 1][m * 16 + lg * 4 + q][wave * 64 + n * 16 + lc] = (__bf16)cell[n][m][q];
      __syncthreads();
      for (int w = tid; w < RPB * 132; w += THR) {
        int r = w / 132, j = w - r * 132;
        int slot = rowslot[r];
        if (slot < 0) continue;
        if (j < 68)
          *(bf8*)(sstate + (size_t)slot * KD + j * 8) = *(const bf8*)&Abuf[cur][r][j * 8];
        else {
          int jj = j - 68;
          *(bf8*)(scell + (size_t)slot * 512 + jj * 8) = *(const bf8*)&Abuf[cur ^ 1][r][jj * 8];
        }
      }
    }
  } else {
    if (valid) out[oidx] = accum;
  }
}

extern "C" void kernel_launch(void* const* d_in, const int* in_sizes, int n_in,
                              void* d_out, int out_size, void* d_ws, size_t ws_size,
                              hipStream_t stream) {
  const float* x     = (const float*)d_in[0];
  const float* Wi_x  = (const float*)d_in[1];
  const float* bi_x  = (const float*)d_in[2];
  const float* Wi_h  = (const float*)d_in[3];
  const float* bi_h  = (const float*)d_in[4];
  const float* Wf_x  = (const float*)d_in[5];
  const float* bf_x  = (const float*)d_in[6];
  const float* Wf_h  = (const float*)d_in[7];
  const float* bf_h  = (const float*)d_in[8];
  const float* Wc_x  = (const float*)d_in[9];
  const float* bc_x  = (const float*)d_in[10];
  const float* Wc_h  = (const float*)d_in[11];
  const float* bc_h  = (const float*)d_in[12];
  const float* Wo_x  = (const float*)d_in[13];
  const float* bo_x  = (const float*)d_in[14];
  const float* Wo_h  = (const float*)d_in[15];
  const float* bo_h  = (const float*)d_in[16];
  const float* hW1   = (const float*)d_in[17];
  const float* hb1   = (const float*)d_in[18];
  const float* hW2   = (const float*)d_in[19];
  const float* hb2   = (const float*)d_in[20];
  const float* oW1   = (const float*)d_in[21];
  const float* ob1   = (const float*)d_in[22];
  const float* oW2   = (const float*)d_in[23];
  const float* ob2   = (const float*)d_in[24];
  const float* oW3   = (const float*)d_in[25];
  const float* ob3   = (const float*)d_in[26];

  char* p = (char*)d_ws;
  __bf16* whT   = (__bf16*)p;                       p += (size_t)2048 * KD * 2;
  __bf16* w1cat = (__bf16*)p;                       p += (size_t)256 * KD * 2;
  float*  w23   = (float*)p;                        p += 512;
  float*  b23   = (float*)p;                        p += 16;
  int*    cnt   = (int*)p;                          p += 240;
  __bf16* sstate= (__bf16*)p;                       p += (size_t)NROW * KD * 2;
  __bf16* scell = (__bf16*)p;                       p += (size_t)NROW * 512 * 2;
  float*  spsum = (float*)p;                        p += (size_t)NROW * 4;
  float*  saccum= (float*)p;                        p += (size_t)NROW * 4;
  int*    sidx  = (int*)p;                          p += (size_t)NROW * 4;

  pack_all<<<dim3(325), dim3(256), 0, stream>>>(
      Wi_h, Wf_h, Wc_h, Wo_h, Wi_x, Wf_x, Wc_x, Wo_x,
      bi_x, bf_x, bc_x, bo_x, bi_h, bf_h, bc_h, bo_h,
      oW1, ob1, hW1, hb1, oW2, ob2, oW3, ob3,
      whT, w1cat, w23, b23, cnt);
  act_pass<true><<<dim3(NROW / RPB), dim3(THR), 0, stream>>>(
      x, whT, w1cat, w23, b23, hW2, hb2,
      sstate, scell, spsum, saccum, sidx, cnt, (float*)d_out);
  act_pass<false><<<dim3(NROW / RPB), dim3(THR), 0, stream>>>(
      x, whT, w1cat, w23, b23, hW2, hb2,
      sstate, scell, spsum, saccum, sidx, cnt, (float*)d_out);
}

// Round 8
// 370.230 us; speedup vs baseline: 1.4794x; 1.4794x over previous
//
#include <hip/hip_runtime.h>
#include <hip/hip_bf16.h>

#define KD   544      // 512 state + x0,x1,1 + pad to 17*32
#define ASTR 552      // LDS row stride (bf16)
#define RPB  64       // rows per block
#define THR  512      // 8 waves
#define T1   3        // pass-1 step count
#define NROW 32768

typedef __bf16 bf8 __attribute__((ext_vector_type(8)));
typedef float f32x4 __attribute__((ext_vector_type(4)));

__device__ __forceinline__ float sigm(float x)  { return 1.0f / (1.0f + __expf(-x)); }
__device__ __forceinline__ float tanh_(float x) { return 2.0f / (1.0f + __expf(-2.0f * x)) - 1.0f; }

// Weights packed in MFMA-fragment order: whT2[((ct*17 + kt)*64 + lane)*8 + e]
// holds B-element [col = ct*16 + (lane&15)][k = kt*32 + (lane>>4)*8 + e].
// A wave's B-fragment load for tile (ct,kt) is then ONE contiguous 1KB burst.
__global__ void pack_all(const float* __restrict__ Wi_h, const float* __restrict__ Wf_h,
                         const float* __restrict__ Wc_h, const float* __restrict__ Wo_h,
                         const float* __restrict__ Wi_x, const float* __restrict__ Wf_x,
                         const float* __restrict__ Wc_x, const float* __restrict__ Wo_x,
                         const float* __restrict__ bi_x, const float* __restrict__ bf_x,
                         const float* __restrict__ bc_x, const float* __restrict__ bo_x,
                         const float* __restrict__ bi_h, const float* __restrict__ bf_h,
                         const float* __restrict__ bc_h, const float* __restrict__ bo_h,
                         const float* __restrict__ outW1, const float* __restrict__ outb1,
                         const float* __restrict__ haltW1, const float* __restrict__ haltb1,
                         const float* __restrict__ outW2, const float* __restrict__ outb2,
                         const float* __restrict__ outW3, const float* __restrict__ outb3,
                         __bf16* __restrict__ whT2, __bf16* __restrict__ w1cat2,
                         float* __restrict__ w23, float* __restrict__ b23,
                         int* __restrict__ cntp)
{
  __shared__ float tile[64][65];
  const int b = blockIdx.x;
  const int tid = threadIdx.x;

  if (b < 256) {
    // gate main: 64x64 tile (g, ct4, kt2)
    const int g = b >> 6, ct4 = (b >> 3) & 7, kt2 = b & 7;
    const int c0 = ct4 * 64, k0 = kt2 * 64;
    const float* Wh = (g == 0) ? Wi_h : (g == 1) ? Wf_h : (g == 2) ? Wc_h : Wo_h;
    const int ty = tid >> 6, tx = tid & 63;
#pragma unroll
    for (int r = 0; r < 16; ++r) {
      int kl = r * 4 + ty;
      tile[kl][tx] = Wh[(size_t)(k0 + kl) * 512 + c0 + tx];
    }
    __syncthreads();
#pragma unroll
    for (int h = 0; h < 2; ++h) {
      int chunk = tid + h * 256;           // 0..511
      int ct_l = chunk >> 7;               // 0..3
      int kt_l = (chunk >> 6) & 1;         // 0..1
      int l    = chunk & 63;
      int cl = ct_l * 16 + (l & 15);
      int kb = kt_l * 32 + (l >> 4) * 8;
      bf8 v;
#pragma unroll
      for (int e = 0; e < 8; ++e) v[e] = (__bf16)tile[kb + e][cl];
      int ct_g = g * 32 + ct4 * 4 + ct_l;
      int kt_g = kt2 * 2 + kt_l;
      *(bf8*)(whT2 + ((size_t)(ct_g * 17 + kt_g) * 64 + l) * 8) = v;
    }
  } else if (b < 288) {
    // gate tail (kt=16): x rows + fused bias
    const int b2 = b - 256;
    const int g = b2 >> 3, ct4 = b2 & 7;
    const float* Wx = (g == 0) ? Wi_x : (g == 1) ? Wf_x : (g == 2) ? Wc_x : Wo_x;
    const float* bx = (g == 0) ? bi_x : (g == 1) ? bf_x : (g == 2) ? bc_x : bo_x;
    const float* bh = (g == 0) ? bi_h : (g == 1) ? bf_h : (g == 2) ? bc_h : bo_h;
    const int ct_l = tid >> 6, l = tid & 63;
    const int c = ct4 * 64 + ct_l * 16 + (l & 15);   // col within gate, 0..511
    const int kb = (l >> 4) * 8;
    bf8 v;
#pragma unroll
    for (int e = 0; e < 8; ++e) {
      int ka = kb + e;                                // 0..31 (k = 512 + ka)
      float f = 0.0f;
      if (ka == 0)      f = Wx[c];
      else if (ka == 1) f = Wx[512 + c];
      else if (ka == 2) f = bx[c] + bh[c];
      v[e] = (__bf16)f;
    }
    int ct_g = g * 32 + ct4 * 4 + ct_l;
    *(bf8*)(whT2 + ((size_t)(ct_g * 17 + 16) * 64 + l) * 8) = v;
  } else if (b < 320) {
    // w1cat main: (src, jt, kt2)
    const int b2 = b - 288;
    const int src = b2 >> 4, jt = (b2 >> 3) & 1, kt2 = b2 & 7;
    const float* W = src ? haltW1 : outW1;
    const int c0 = jt * 64, k0 = kt2 * 64;
    const int ty = tid >> 6, tx = tid & 63;
#pragma unroll
    for (int r = 0; r < 16; ++r) {
      int kl = r * 4 + ty;
      tile[kl][tx] = W[(size_t)(k0 + kl) * 128 + c0 + tx];
    }
    __syncthreads();
#pragma unroll
    for (int h = 0; h < 2; ++h) {
      int chunk = tid + h * 256;
      int ct_l = chunk >> 7;
      int kt_l = (chunk >> 6) & 1;
      int l    = chunk & 63;
      int cl = ct_l * 16 + (l & 15);
      int kb = kt_l * 32 + (l >> 4) * 8;
      bf8 v;
#pragma unroll
      for (int e = 0; e < 8; ++e) v[e] = (__bf16)tile[kb + e][cl];
      int ct_g = src * 8 + jt * 4 + ct_l;
      int kt_g = kt2 * 2 + kt_l;
      *(bf8*)(w1cat2 + ((size_t)(ct_g * 17 + kt_g) * 64 + l) * 8) = v;
    }
  } else if (b < 324) {
    // w1cat tail (kt=16): bias at k=514
    const int grp = b - 320;                  // 0..3, 64 cols each
    const int ct_l = tid >> 6, l = tid & 63;
    const int j = grp * 64 + ct_l * 16 + (l & 15);   // 0..255
    const float bias = (j < 128) ? outb1[j] : haltb1[j - 128];
    const int kb = (l >> 4) * 8;
    bf8 v;
#pragma unroll
    for (int e = 0; e < 8; ++e) {
      int ka = kb + e;
      v[e] = (__bf16)((ka == 2) ? bias : 0.0f);
    }
    int ct_g = grp * 4 + ct_l;
    *(bf8*)(w1cat2 + ((size_t)(ct_g * 17 + 16) * 64 + l) * 8) = v;
  } else {
    const int c1 = tid;
    if (c1 < 128) {
      float s = 0.0f;
      for (int c2 = 0; c2 < 128; ++c2) s += outW2[c1 * 128 + c2] * outW3[c2];
      w23[c1] = s;
    }
    if (c1 == 0) {
      float bb = 0.0f;
      for (int c2 = 0; c2 < 128; ++c2) bb += outb2[c2] * outW3[c2];
      b23[0] = bb + outb3[0];
      cntp[0] = 0;
    }
  }
}

template<bool P1>
__global__ __launch_bounds__(THR, 2) void act_pass(
    const float* __restrict__ x,
    const __bf16* __restrict__ whT2,
    const __bf16* __restrict__ w1cat2,
    const float* __restrict__ w23,
    const float* __restrict__ b23p,
    const float* __restrict__ haltW2,
    const float* __restrict__ haltb2,
    __bf16* __restrict__ sstate,
    __bf16* __restrict__ scell,
    float* __restrict__ spsum,
    float* __restrict__ saccum,
    int* __restrict__ sidx,
    int* __restrict__ cntp,
    float* __restrict__ out)
{
  int cnt_v = 0, sbase = 0;
  if constexpr (!P1) {
    cnt_v = cntp[0];
    sbase = blockIdx.x * RPB;
    if (sbase >= cnt_v) return;
  }

  __shared__ __align__(16) __bf16 Abuf[2][RPB][ASTR];
  __shared__ float wv[256];
  __shared__ float partials[8][RPB];
  __shared__ int anyact_s;
  __shared__ int rowslot[RPB];

  const int tid  = threadIdx.x;
  const int wave = tid >> 6;
  const int lane = tid & 63;
  const int lg   = lane >> 4;
  const int lc   = lane & 15;
  const int row0 = blockIdx.x * RPB;

  if (tid < 256) wv[tid] = (tid < 128) ? w23[tid] : haltW2[tid - 128];

  if constexpr (P1) {
    for (int w = tid; w < 2 * RPB * 69; w += THR) {
      int bb  = w / (RPB * 69);
      int rem = w - bb * (RPB * 69);
      int r   = rem / 69;
      int j   = rem - r * 69;
      bf8 v;
#pragma unroll
      for (int e = 0; e < 8; ++e) v[e] = (__bf16)0.0f;
      if (j == 64) {
        v[0] = (__bf16)x[(row0 + r) * 2 + 0];
        v[1] = (__bf16)x[(row0 + r) * 2 + 1];
        v[2] = (__bf16)1.0f;
      }
      *(bf8*)&Abuf[bb][r][j * 8] = v;
    }
  } else {
    for (int w = tid; w < RPB * 68; w += THR) {
      int r = w / 68, j = w - r * 68;
      int slot = sbase + r;
      bf8 v;
#pragma unroll
      for (int e = 0; e < 8; ++e) v[e] = (__bf16)0.0f;
      if (slot < cnt_v) v = *(const bf8*)(sstate + (size_t)slot * KD + j * 8);
      *(bf8*)&Abuf[0][r][j * 8] = v;
      if (j >= 64) *(bf8*)&Abuf[1][r][j * 8] = v;
    }
    for (int w = tid; w < RPB * 64; w += THR) {
      int r = w / 64, j = w - r * 64;
      int slot = sbase + r;
      bf8 v;
#pragma unroll
      for (int e = 0; e < 8; ++e) v[e] = (__bf16)0.0f;
      if (slot < cnt_v) v = *(const bf8*)(scell + (size_t)slot * 512 + j * 8);
      *(bf8*)&Abuf[1][r][j * 8] = v;
    }
  }
  if (tid == 0) anyact_s = 1;
  __syncthreads();

  float cell[4][4][4];
  if constexpr (P1) {
#pragma unroll
    for (int n = 0; n < 4; ++n)
#pragma unroll
      for (int m = 0; m < 4; ++m)
#pragma unroll
        for (int q = 0; q < 4; ++q) cell[n][m][q] = 0.0f;
  } else {
#pragma unroll
    for (int n = 0; n < 4; ++n)
#pragma unroll
      for (int m = 0; m < 4; ++m)
#pragma unroll
        for (int q = 0; q < 4; ++q)
          cell[n][m][q] = (float)Abuf[1][m * 16 + lg * 4 + q][wave * 64 + n * 16 + lc];
  }

  bool  valid, active;
  float p_sum, accum;
  int   oidx;
  if constexpr (P1) {
    valid = (tid < 64); active = valid;
    p_sum = 0.0f; accum = 0.0f; oidx = row0 + tid;
  } else {
    int slot = sbase + tid;
    valid = (tid < 64) && (slot < cnt_v);
    active = valid;
    p_sum = valid ? spsum[slot]  : 1.0f;
    accum = valid ? saccum[slot] : 0.0f;
    oidx  = valid ? sidx[slot]   : 0;
    __syncthreads();
  }

  const float b23 = b23p[0];
  const float bh2 = haltb2[0];
  const f32x4 zero4 = {0.0f, 0.0f, 0.0f, 0.0f};

  int cur = 0;
  const int T0 = P1 ? 0 : T1;
  const int TE = P1 ? T1 : 32;
  for (int t = T0; t < TE; ++t) {
    const int kstart = (P1 && t == 0) ? 16 : 0;
    // ---------------- gate GEMM (64 x 2048) + LSTM update ----------------
#pragma unroll
    for (int n = 0; n < 4; ++n) {
      const int colb = wave * 64 + n * 16 + lc;
      const int ctn = wave * 4 + n;                 // within-gate col-tile idx
      // fragment-order B pointers: one contiguous 1KB burst per (ct, kt)
      const __bf16* bp0 = whT2 + ((size_t)((0 * 32 + ctn) * 17) * 64 + lane) * 8;
      const __bf16* bp1 = whT2 + ((size_t)((1 * 32 + ctn) * 17) * 64 + lane) * 8;
      const __bf16* bp2 = whT2 + ((size_t)((2 * 32 + ctn) * 17) * 64 + lane) * 8;
      const __bf16* bp3 = whT2 + ((size_t)((3 * 32 + ctn) * 17) * 64 + lane) * 8;
      f32x4 acc[4][4];
#pragma unroll
      for (int g = 0; g < 4; ++g)
#pragma unroll
        for (int m = 0; m < 4; ++m) acc[g][m] = zero4;

      bf8 b0 = *(const bf8*)(bp0 + kstart * 512);
      bf8 b1 = *(const bf8*)(bp1 + kstart * 512);
      bf8 b2 = *(const bf8*)(bp2 + kstart * 512);
      bf8 b3 = *(const bf8*)(bp3 + kstart * 512);
#pragma unroll 1
      for (int kk = kstart; kk < 16; ++kk) {
        bf8 av[4];
#pragma unroll
        for (int m = 0; m < 4; ++m)
          av[m] = *(const bf8*)&Abuf[cur][m * 16 + lc][kk * 32 + lg * 8];
        bf8 nb0 = *(const bf8*)(bp0 + (kk + 1) * 512);
        bf8 nb1 = *(const bf8*)(bp1 + (kk + 1) * 512);
        bf8 nb2 = *(const bf8*)(bp2 + (kk + 1) * 512);
        bf8 nb3 = *(const bf8*)(bp3 + (kk + 1) * 512);
#pragma unroll
        for (int m = 0; m < 4; ++m) {
          acc[0][m] = __builtin_amdgcn_mfma_f32_16x16x32_bf16(av[m], b0, acc[0][m], 0, 0, 0);
          acc[1][m] = __builtin_amdgcn_mfma_f32_16x16x32_bf16(av[m], b1, acc[1][m], 0, 0, 0);
          acc[2][m] = __builtin_amdgcn_mfma_f32_16x16x32_bf16(av[m], b2, acc[2][m], 0, 0, 0);
          acc[3][m] = __builtin_amdgcn_mfma_f32_16x16x32_bf16(av[m], b3, acc[3][m], 0, 0, 0);
        }
        b0 = nb0; b1 = nb1; b2 = nb2; b3 = nb3;
      }
      { // tail k-step (x0,x1,bias rows; kt=16)
        bf8 av[4];
#pragma unroll
        for (int m = 0; m < 4; ++m)
          av[m] = *(const bf8*)&Abuf[cur][m * 16 + lc][16 * 32 + lg * 8];
#pragma unroll
        for (int m = 0; m < 4; ++m) {
          acc[0][m] = __builtin_amdgcn_mfma_f32_16x16x32_bf16(av[m], b0, acc[0][m], 0, 0, 0);
          acc[1][m] = __builtin_amdgcn_mfma_f32_16x16x32_bf16(av[m], b1, acc[1][m], 0, 0, 0);
          acc[2][m] = __builtin_amdgcn_mfma_f32_16x16x32_bf16(av[m], b2, acc[2][m], 0, 0, 0);
          acc[3][m] = __builtin_amdgcn_mfma_f32_16x16x32_bf16(av[m], b3, acc[3][m], 0, 0, 0);
        }
      }
      // LSTM update epilogue. D layout: col = lane&15, row = (lane>>4)*4 + reg (+m*16)
#pragma unroll
      for (int m = 0; m < 4; ++m) {
#pragma unroll
        for (int q = 0; q < 4; ++q) {
          float iv = sigm(acc[0][m][q]);
          float fv = sigm(acc[1][m][q]);
          float cv = tanh_(acc[2][m][q]);
          float ov = sigm(acc[3][m][q]);
          float cn = fv * cell[n][m][q] + iv * cv;
          cell[n][m][q] = cn;
          float h = ov * tanh_(cn);
          Abuf[cur ^ 1][m * 16 + lg * 4 + q][colb] = (__bf16)h;
        }
      }
    }
    __syncthreads();
    // ---------------- head GEMM (64 x 256 = out|halt) + folded dots ----------------
    {
      const __bf16* hp0 = w1cat2 + ((size_t)((wave * 2 + 0) * 17) * 64 + lane) * 8;
      const __bf16* hp1 = w1cat2 + ((size_t)((wave * 2 + 1) * 17) * 64 + lane) * 8;
      f32x4 hacc[2][4];
#pragma unroll
      for (int n2 = 0; n2 < 2; ++n2)
#pragma unroll
        for (int m = 0; m < 4; ++m) hacc[n2][m] = zero4;
      bf8 hb0 = *(const bf8*)(hp0);
      bf8 hb1 = *(const bf8*)(hp1);
#pragma unroll 1
      for (int kk = 0; kk < 16; ++kk) {
        bf8 av[4];
#pragma unroll
        for (int m = 0; m < 4; ++m)
          av[m] = *(const bf8*)&Abuf[cur ^ 1][m * 16 + lc][kk * 32 + lg * 8];
        bf8 nb0 = *(const bf8*)(hp0 + (kk + 1) * 512);
        bf8 nb1 = *(const bf8*)(hp1 + (kk + 1) * 512);
#pragma unroll
        for (int m = 0; m < 4; ++m) {
          hacc[0][m] = __builtin_amdgcn_mfma_f32_16x16x32_bf16(av[m], hb0, hacc[0][m], 0, 0, 0);
          hacc[1][m] = __builtin_amdgcn_mfma_f32_16x16x32_bf16(av[m], hb1, hacc[1][m], 0, 0, 0);
        }
        hb0 = nb0; hb1 = nb1;
      }
      {
        bf8 av[4];
#pragma unroll
        for (int m = 0; m < 4; ++m)
          av[m] = *(const bf8*)&Abuf[cur ^ 1][m * 16 + lc][16 * 32 + lg * 8];
#pragma unroll
        for (int m = 0; m < 4; ++m) {
          hacc[0][m] = __builtin_amdgcn_mfma_f32_16x16x32_bf16(av[m], hb0, hacc[0][m], 0, 0, 0);
          hacc[1][m] = __builtin_amdgcn_mfma_f32_16x16x32_bf16(av[m], hb1, hacc[1][m], 0, 0, 0);
        }
      }
      const float wv0 = wv[wave * 32 + lc];
      const float wv1 = wv[wave * 32 + 16 + lc];
#pragma unroll
      for (int m = 0; m < 4; ++m) {
#pragma unroll
        for (int q = 0; q < 4; ++q) {
          float s = fmaxf(hacc[0][m][q], 0.0f) * wv0 + fmaxf(hacc[1][m][q], 0.0f) * wv1;
          s += __shfl_xor(s, 1, 64);
          s += __shfl_xor(s, 2, 64);
          s += __shfl_xor(s, 4, 64);
          s += __shfl_xor(s, 8, 64);
          if (lc == 0) partials[wave][m * 16 + lg * 4 + q] = s;
        }
      }
    }
    __syncthreads();
    // ---------------- ACT bookkeeping ----------------
    if (tid < 64) {
      float od = partials[0][tid] + partials[1][tid] + partials[2][tid] + partials[3][tid] + b23;
      float hd = partials[4][tid] + partials[5][tid] + partials[6][tid] + partials[7][tid] + bh2;
      float outv  = sigm(od);
      float haltv = sigm(hd);
      if (active) {
        float pn  = p_sum + haltv;
        bool  fin = (pn >= 0.999f) || (t == 31);
        accum += outv * (fin ? (haltv + (1.0f - pn)) : haltv);
        p_sum  = fin ? 1.0f : pn;
        active = !fin;
      }
      unsigned long long mk = __ballot(active);
      if (tid == 0) anyact_s = (mk != 0ull) ? 1 : 0;
    }
    __syncthreads();
    if (!anyact_s) break;
    cur ^= 1;
  }

  if constexpr (P1) {
    if (tid < 64) {
      unsigned long long mk = __ballot(active);
      int base = 0;
      if (lane == 0 && mk) base = atomicAdd(cntp, __popcll(mk));
      base = __shfl(base, 0, 64);
      int rank = __popcll(mk & ((1ull << lane) - 1ull));
      int slot = active ? (base + rank) : -1;
      rowslot[tid] = slot;
      if (active) {
        spsum[slot]  = p_sum;
        saccum[slot] = accum;
        sidx[slot]   = oidx;
      } else {
        out[oidx] = accum;
      }
      if (tid == 0) anyact_s = (mk != 0ull) ? 1 : 0;
    }
    __syncthreads();
    if (anyact_s) {
#pragma unroll
      for (int n = 0; n < 4; ++n)
#pragma unroll
        for (int m = 0; m < 4; ++m)
#pragma unroll
          for (int q = 0; q < 4; ++q)
            Abuf[cur ^ 1][m * 16 + lg * 4 + q][wave * 64 + n * 16 + lc] = (__bf16)cell[n][m][q];
      __syncthreads();
      for (int w = tid; w < RPB * 132; w += THR) {
        int r = w / 132, j = w - r * 132;
        int slot = rowslot[r];
        if (slot < 0) continue;
        if (j < 68)
          *(bf8*)(sstate + (size_t)slot * KD + j * 8) = *(const bf8*)&Abuf[cur][r][j * 8];
        else {
          int jj = j - 68;
          *(bf8*)(scell + (size_t)slot * 512 + jj * 8) = *(const bf8*)&Abuf[cur ^ 1][r][jj * 8];
        }
      }
    }
  } else {
    if (valid) out[oidx] = accum;
  }
}

extern "C" void kernel_launch(void* const* d_in, const int* in_sizes, int n_in,
                              void* d_out, int out_size, void* d_ws, size_t ws_size,
                              hipStream_t stream) {
  const float* x     = (const float*)d_in[0];
  const float* Wi_x  = (const float*)d_in[1];
  const float* bi_x  = (const float*)d_in[2];
  const float* Wi_h  = (const float*)d_in[3];
  const float* bi_h  = (const float*)d_in[4];
  const float* Wf_x  = (const float*)d_in[5];
  const float* bf_x  = (const float*)d_in[6];
  const float* Wf_h  = (const float*)d_in[7];
  const float* bf_h  = (const float*)d_in[8];
  const float* Wc_x  = (const float*)d_in[9];
  const float* bc_x  = (const float*)d_in[10];
  const float* Wc_h  = (const float*)d_in[11];
  const float* bc_h  = (const float*)d_in[12];
  const float* Wo_x  = (const float*)d_in[13];
  const float* bo_x  = (const float*)d_in[14];
  const float* Wo_h  = (const float*)d_in[15];
  const float* bo_h  = (const float*)d_in[16];
  const float* hW1   = (const float*)d_in[17];
  const float* hb1   = (const float*)d_in[18];
  const float* hW2   = (const float*)d_in[19];
  const float* hb2   = (const float*)d_in[20];
  const float* oW1   = (const float*)d_in[21];
  const float* ob1   = (const float*)d_in[22];
  const float* oW2   = (const float*)d_in[23];
  const float* ob2   = (const float*)d_in[24];
  const float* oW3   = (const float*)d_in[25];
  const float* ob3   = (const float*)d_in[26];

  char* p = (char*)d_ws;
  __bf16* whT2  = (__bf16*)p;                       p += (size_t)2048 * KD * 2;
  __bf16* w1cat2= (__bf16*)p;                       p += (size_t)256 * KD * 2;
  float*  w23   = (float*)p;                        p += 512;
  float*  b23   = (float*)p;                        p += 16;
  int*    cnt   = (int*)p;                          p += 240;
  __bf16* sstate= (__bf16*)p;                       p += (size_t)NROW * KD * 2;
  __bf16* scell = (__bf16*)p;                       p += (size_t)NROW * 512 * 2;
  float*  spsum = (float*)p;                        p += (size_t)NROW * 4;
  float*  saccum= (float*)p;                        p += (size_t)NROW * 4;
  int*    sidx  = (int*)p;                          p += (size_t)NROW * 4;

  pack_all<<<dim3(325), dim3(256), 0, stream>>>(
      Wi_h, Wf_h, Wc_h, Wo_h, Wi_x, Wf_x, Wc_x, Wo_x,
      bi_x, bf_x, bc_x, bo_x, bi_h, bf_h, bc_h, bo_h,
      oW1, ob1, hW1, hb1, oW2, ob2, oW3, ob3,
      whT2, w1cat2, w23, b23, cnt);
  act_pass<true><<<dim3(NROW / RPB), dim3(THR), 0, stream>>>(
      x, whT2, w1cat2, w23, b23, hW2, hb2,
      sstate, scell, spsum, saccum, sidx, cnt, (float*)d_out);
  act_pass<false><<<dim3(NROW / RPB), dim3(THR), 0, stream>>>(
      x, whT2, w1cat2, w23, b23, hW2, hb2,
      sstate, scell, spsum, saccum, sidx, cnt, (float*)d_out);
}